// Round 6
// baseline (104.291 us; speedup 1.0000x reference)
//
#include <hip/hip_runtime.h>
#include <hip/hip_fp16.h>
#include <math.h>

#define LSEQ 4096
#define TDIM 25
#define BDIM 257
#define RDIM 8
#define KDIM 3

#define S_CHUNK 8
#define W_WARM 16
#define TOT (S_CHUNK + W_WARM)     // 24 steps per thread
#define NCHUNK (LSEQ / S_CHUNK)    // 512

__device__ __forceinline__ float rcp_f(float x) {
    return __builtin_amdgcn_rcpf(x);    // v_rcp_f32, ~1 ULP
}
__device__ __forceinline__ float elu_f(float x) {
    return x > 0.f ? x : (__expf(x) - 1.f);
}
__device__ __forceinline__ float sig_f(float x) {
    return rcp_f(1.f + __expf(-x));
}
__device__ __forceinline__ float tanh_f(float x) {
    float e = __expf(2.f * x);
    return 1.f - 2.f * rcp_f(e + 1.f);
}

// ---------------- Kernel 1: encoder (parallel over L x B) ----------------
__global__ __launch_bounds__(320) void k_enc(
    const float* __restrict__ x, const float* __restrict__ knobs,
    const float* __restrict__ W_enc, const float* __restrict__ b_enc,
    const float* __restrict__ W_enc2, const float* __restrict__ b_enc2,
    const float* __restrict__ W_enc3, const float* __restrict__ b_enc3,
    const float* __restrict__ Wk, const float* __restrict__ bk,
    __half2* __restrict__ z_enc, float* __restrict__ kn)
{
    const int l = blockIdx.x;
    const int b = threadIdx.x;
    if (b < BDIM) {
        const float* xl = x + (size_t)l * TDIM * BDIM + b;
        float xr[TDIM];
        #pragma unroll
        for (int t = 0; t < TDIM; ++t) xr[t] = xl[(size_t)t * BDIM];
        float z1[RDIM];
        #pragma unroll
        for (int r = 0; r < RDIM; ++r) {
            float a = b_enc[r];
            #pragma unroll
            for (int t = 0; t < TDIM; ++t) a = fmaf(W_enc[r * TDIM + t], xr[t], a);
            z1[r] = elu_f(a);
        }
        float z2[RDIM / 2];
        #pragma unroll
        for (int r = 0; r < RDIM / 2; ++r) {
            float a = b_enc2[r];
            #pragma unroll
            for (int j = 0; j < RDIM; ++j) a = fmaf(W_enc2[r * RDIM + j], z1[j], a);
            z2[r] = elu_f(a);
        }
        float z30 = b_enc3[0], z31 = b_enc3[1];
        #pragma unroll
        for (int j = 0; j < RDIM / 2; ++j) {
            z30 = fmaf(W_enc3[j], z2[j], z30);
            z31 = fmaf(W_enc3[RDIM / 2 + j], z2[j], z31);
        }
        z_enc[(size_t)l * BDIM + b] = __floats2half2_rn(elu_f(z30), elu_f(z31));
    } else if (b == BDIM) {
        float k0 = knobs[l * KDIM + 0], k1 = knobs[l * KDIM + 1], k2 = knobs[l * KDIM + 2];
        float2 kv;
        kv.x = bk[0] + Wk[0 * 5 + 2] * k0 + Wk[0 * 5 + 3] * k1 + Wk[0 * 5 + 4] * k2;
        kv.y = bk[1] + Wk[1 * 5 + 2] * k0 + Wk[1 * 5 + 3] * k1 + Wk[1 * 5 + 4] * k2;
        reinterpret_cast<float2*>(kn)[l] = kv;
    }
}

// ---------------- Kernel 2: fused LSTM1 -> mid -> LSTM2 -> decoder ----------------
struct LWeights {
    float wi1[8][2], wh1[8][2], bb1[8];
    float wi2[8][2], wh2[8][2], bb2[8];
    float wk00, wk01, wk10, wk11;
};
struct LState {
    float h1x, h1y, c1x, c1y, h2x, h2y, c2x, c2y;
};

__device__ __forceinline__ void lstm_step(
    LState& s, float2 xe, float2 kv, const LWeights& w)
{
    // ---- LSTM1 ---- gate order i,f,g,o (4H=8, H=2)
    float g[8];
    #pragma unroll
    for (int j = 0; j < 8; ++j)
        g[j] = fmaf(w.wh1[j][1], s.h1y, fmaf(w.wh1[j][0], s.h1x,
               fmaf(w.wi1[j][1], xe.y, fmaf(w.wi1[j][0], xe.x, w.bb1[j]))));
    s.c1x = fmaf(sig_f(g[2]), s.c1x, sig_f(g[0]) * tanh_f(g[4]));
    s.c1y = fmaf(sig_f(g[3]), s.c1y, sig_f(g[1]) * tanh_f(g[5]));
    s.h1x = sig_f(g[6]) * tanh_f(s.c1x);
    s.h1y = sig_f(g[7]) * tanh_f(s.c1y);
    // ---- mid (knobs) layer ----
    float e0 = elu_f(s.h1x), e1 = elu_f(s.h1y);
    float m0 = elu_f(fmaf(w.wk01, e1, fmaf(w.wk00, e0, kv.x)));
    float m1 = elu_f(fmaf(w.wk11, e1, fmaf(w.wk10, e0, kv.y)));
    // ---- LSTM2 ----
    float g2[8];
    #pragma unroll
    for (int j = 0; j < 8; ++j)
        g2[j] = fmaf(w.wh2[j][1], s.h2y, fmaf(w.wh2[j][0], s.h2x,
                fmaf(w.wi2[j][1], m1, fmaf(w.wi2[j][0], m0, w.bb2[j]))));
    s.c2x = fmaf(sig_f(g2[2]), s.c2x, sig_f(g2[0]) * tanh_f(g2[4]));
    s.c2y = fmaf(sig_f(g2[3]), s.c2y, sig_f(g2[1]) * tanh_f(g2[5]));
    s.h2x = sig_f(g2[6]) * tanh_f(s.c2x);
    s.h2y = sig_f(g2[7]) * tanh_f(s.c2y);
}

// Block = 320 threads covering ALL 257 batch rows of ONE chunk of 8 l's.
// All global IO of a block is one contiguous ~205 KB region (full DRAM bursts).
__global__ __launch_bounds__(320) void k_fused(
    const __half2* __restrict__ z_enc, const float* __restrict__ kn,
    const float* __restrict__ Wih1, const float* __restrict__ Whh1,
    const float* __restrict__ bih1, const float* __restrict__ bhh1,
    const float* __restrict__ Wk,
    const float* __restrict__ Wih2, const float* __restrict__ Whh2,
    const float* __restrict__ bih2, const float* __restrict__ bhh2,
    const float* __restrict__ W_dec3, const float* __restrict__ b_dec3,
    const float* __restrict__ W_dec2, const float* __restrict__ b_dec2,
    const float* __restrict__ W_dec, const float* __restrict__ b_dec,
    const float* __restrict__ x, float* __restrict__ out)
{
    const int tid = threadIdx.x;
    const int bb = tid < BDIM ? tid : BDIM - 1;   // clamp for safe reads
    const bool active = tid < BDIM;
    const int chunk = blockIdx.x;
    const int l0 = chunk * S_CHUNK;
    const int ls = l0 - W_WARM;                   // may be negative (chunks 0..1)

    const float2* knv = reinterpret_cast<const float2*>(kn);

    // ---- preload z window into registers (24 independent coalesced loads) ----
    __half2 zr[TOT];
    #pragma unroll
    for (int i = 0; i < TOT; ++i) {
        int l = ls + i; int lc = l < 0 ? 0 : l;
        zr[i] = z_enc[(size_t)lc * BDIM + bb];
    }

    // ---- weights (lane-invariant -> scalar regs) ----
    LWeights w;
    #pragma unroll
    for (int j = 0; j < 8; ++j) {
        w.wi1[j][0] = Wih1[j * 2]; w.wi1[j][1] = Wih1[j * 2 + 1];
        w.wh1[j][0] = Whh1[j * 2]; w.wh1[j][1] = Whh1[j * 2 + 1];
        w.bb1[j] = bih1[j] + bhh1[j];
        w.wi2[j][0] = Wih2[j * 2]; w.wi2[j][1] = Wih2[j * 2 + 1];
        w.wh2[j][0] = Whh2[j * 2]; w.wh2[j][1] = Whh2[j * 2 + 1];
        w.bb2[j] = bih2[j] + bhh2[j];
    }
    w.wk00 = Wk[0]; w.wk01 = Wk[1]; w.wk10 = Wk[5]; w.wk11 = Wk[6];

    LState s = {0.f, 0.f, 0.f, 0.f, 0.f, 0.f, 0.f, 0.f};

    // ---- warmup (no output) ----
    #pragma unroll
    for (int i = 0; i < W_WARM; ++i) {
        const int l = ls + i;
        if (l < 0) continue;                      // wave-uniform: state stays zero
        float2 xe = __half22float2(zr[i]);
        lstm_step(s, xe, knv[l], w);
    }

    // ---- body + decoder front half: d2 per body step (static indexing) ----
    float d2a[S_CHUNK][8];
    #pragma unroll
    for (int i = 0; i < S_CHUNK; ++i) {
        float2 xe = __half22float2(zr[W_WARM + i]);
        lstm_step(s, xe, knv[l0 + i], w);
        float e0 = elu_f(s.h2x), e1 = elu_f(s.h2y);
        float d3[4];
        #pragma unroll
        for (int r = 0; r < 4; ++r)
            d3[r] = elu_f(fmaf(W_dec3[r * 2 + 1], e1, fmaf(W_dec3[r * 2], e0, b_dec3[r])));
        #pragma unroll
        for (int r = 0; r < 8; ++r) {
            float a = b_dec2[r];
            #pragma unroll
            for (int j = 0; j < 4; ++j) a = fmaf(W_dec2[r * 4 + j], d3[j], a);
            d2a[i][r] = elu_f(a);
        }
    }

    // ---- output: block walks its contiguous 8*25*1028B region ----
    const float* xb = x + bb;
    float* ob = out + bb;
    #pragma unroll
    for (int i = 0; i < S_CHUNK; ++i) {
        #pragma unroll 5
        for (int t = 0; t < TDIM; ++t) {
            const size_t idx = ((size_t)(l0 + i) * TDIM + t) * BDIM;
            float a = b_dec[t] + xb[idx];
            #pragma unroll
            for (int r = 0; r < 8; ++r) a = fmaf(W_dec[t * 8 + r], d2a[i][r], a);
            if (active) ob[idx] = elu_f(a);
        }
    }
}

extern "C" void kernel_launch(void* const* d_in, const int* in_sizes, int n_in,
                              void* d_out, int out_size, void* d_ws, size_t ws_size,
                              hipStream_t stream) {
    (void)in_sizes; (void)n_in; (void)out_size; (void)ws_size;
    const float* x_input = (const float*)d_in[0];
    const float* knobs   = (const float*)d_in[1];
    const float* W_enc   = (const float*)d_in[2];
    const float* b_enc   = (const float*)d_in[3];
    const float* W_enc2  = (const float*)d_in[4];
    const float* b_enc2  = (const float*)d_in[5];
    const float* W_enc3  = (const float*)d_in[6];
    const float* b_enc3  = (const float*)d_in[7];
    const float* Wih1    = (const float*)d_in[8];
    const float* Whh1    = (const float*)d_in[9];
    const float* bih1    = (const float*)d_in[10];
    const float* bhh1    = (const float*)d_in[11];
    const float* W_knobs = (const float*)d_in[12];
    const float* b_knobs = (const float*)d_in[13];
    const float* Wih2    = (const float*)d_in[14];
    const float* Whh2    = (const float*)d_in[15];
    const float* bih2    = (const float*)d_in[16];
    const float* bhh2    = (const float*)d_in[17];
    const float* W_dec3  = (const float*)d_in[18];
    const float* b_dec3  = (const float*)d_in[19];
    const float* W_dec2  = (const float*)d_in[20];
    const float* b_dec2  = (const float*)d_in[21];
    const float* W_dec   = (const float*)d_in[22];
    const float* b_dec   = (const float*)d_in[23];

    __half2* z_enc = (__half2*)d_ws;                       // L*B half2 (4.2 MB)
    float* kn = (float*)((char*)d_ws + (size_t)LSEQ * BDIM * sizeof(__half2));

    k_enc<<<dim3(LSEQ), dim3(320), 0, stream>>>(
        x_input, knobs, W_enc, b_enc, W_enc2, b_enc2, W_enc3, b_enc3,
        W_knobs, b_knobs, z_enc, kn);
    k_fused<<<dim3(NCHUNK), dim3(320), 0, stream>>>(
        z_enc, kn, Wih1, Whh1, bih1, bhh1, W_knobs,
        Wih2, Whh2, bih2, bhh2,
        W_dec3, b_dec3, W_dec2, b_dec2, W_dec, b_dec,
        x_input, (float*)d_out);
}

// Round 7
// 94.114 us; speedup vs baseline: 1.1081x; 1.1081x over previous
//
#include <hip/hip_runtime.h>
#include <hip/hip_fp16.h>
#include <math.h>

#define LSEQ 4096
#define TDIM 25
#define BDIM 257
#define RDIM 8
#define KDIM 3

#define S_CHUNK 8
#define W_WARM 16
#define TOT (S_CHUNK + W_WARM)     // 24 steps per thread
#define NCHUNK (LSEQ / S_CHUNK)    // 512

__device__ __forceinline__ float rcp_f(float x) {
    return __builtin_amdgcn_rcpf(x);    // v_rcp_f32, ~1 ULP
}
__device__ __forceinline__ float elu_f(float x) {
    return x > 0.f ? x : (__expf(x) - 1.f);
}
__device__ __forceinline__ float sig_f(float x) {
    return rcp_f(1.f + __expf(-x));
}
__device__ __forceinline__ float tanh_f(float x) {
    float e = __expf(2.f * x);
    return 1.f - 2.f * rcp_f(e + 1.f);
}

// ---------------- Kernel 1: encoder (parallel over L x B) ----------------
__global__ __launch_bounds__(320) void k_enc(
    const float* __restrict__ x, const float* __restrict__ knobs,
    const float* __restrict__ W_enc, const float* __restrict__ b_enc,
    const float* __restrict__ W_enc2, const float* __restrict__ b_enc2,
    const float* __restrict__ W_enc3, const float* __restrict__ b_enc3,
    const float* __restrict__ Wk, const float* __restrict__ bk,
    __half2* __restrict__ z_enc, float* __restrict__ kn)
{
    const int l = blockIdx.x;
    const int b = threadIdx.x;
    if (b < BDIM) {
        const float* xl = x + (size_t)l * TDIM * BDIM + b;
        float xr[TDIM];
        #pragma unroll
        for (int t = 0; t < TDIM; ++t) xr[t] = xl[(size_t)t * BDIM];
        float z1[RDIM];
        #pragma unroll
        for (int r = 0; r < RDIM; ++r) {
            float a = b_enc[r];
            #pragma unroll
            for (int t = 0; t < TDIM; ++t) a = fmaf(W_enc[r * TDIM + t], xr[t], a);
            z1[r] = elu_f(a);
        }
        float z2[RDIM / 2];
        #pragma unroll
        for (int r = 0; r < RDIM / 2; ++r) {
            float a = b_enc2[r];
            #pragma unroll
            for (int j = 0; j < RDIM; ++j) a = fmaf(W_enc2[r * RDIM + j], z1[j], a);
            z2[r] = elu_f(a);
        }
        float z30 = b_enc3[0], z31 = b_enc3[1];
        #pragma unroll
        for (int j = 0; j < RDIM / 2; ++j) {
            z30 = fmaf(W_enc3[j], z2[j], z30);
            z31 = fmaf(W_enc3[RDIM / 2 + j], z2[j], z31);
        }
        z_enc[(size_t)l * BDIM + b] = __floats2half2_rn(elu_f(z30), elu_f(z31));
    } else if (b == BDIM) {
        float k0 = knobs[l * KDIM + 0], k1 = knobs[l * KDIM + 1], k2 = knobs[l * KDIM + 2];
        float2 kv;
        kv.x = bk[0] + Wk[0 * 5 + 2] * k0 + Wk[0 * 5 + 3] * k1 + Wk[0 * 5 + 4] * k2;
        kv.y = bk[1] + Wk[1 * 5 + 2] * k0 + Wk[1 * 5 + 3] * k1 + Wk[1 * 5 + 4] * k2;
        reinterpret_cast<float2*>(kn)[l] = kv;
    }
}

// ---------------- Kernel 2: fused LSTM1 -> mid -> LSTM2 -> decoder ----------------
struct LWeights {
    float wi1[8][2], wh1[8][2], bb1[8];
    float wi2[8][2], wh2[8][2], bb2[8];
    float wk00, wk01, wk10, wk11;
};
struct LState {
    float h1x, h1y, c1x, c1y, h2x, h2y, c2x, c2y;
};

__device__ __forceinline__ void lstm_step(
    LState& s, float2 xe, float2 kv, const LWeights& w)
{
    // ---- LSTM1 ---- gate order i,f,g,o (4H=8, H=2)
    float g[8];
    #pragma unroll
    for (int j = 0; j < 8; ++j)
        g[j] = fmaf(w.wh1[j][1], s.h1y, fmaf(w.wh1[j][0], s.h1x,
               fmaf(w.wi1[j][1], xe.y, fmaf(w.wi1[j][0], xe.x, w.bb1[j]))));
    s.c1x = fmaf(sig_f(g[2]), s.c1x, sig_f(g[0]) * tanh_f(g[4]));
    s.c1y = fmaf(sig_f(g[3]), s.c1y, sig_f(g[1]) * tanh_f(g[5]));
    s.h1x = sig_f(g[6]) * tanh_f(s.c1x);
    s.h1y = sig_f(g[7]) * tanh_f(s.c1y);
    // ---- mid (knobs) layer ----
    float e0 = elu_f(s.h1x), e1 = elu_f(s.h1y);
    float m0 = elu_f(fmaf(w.wk01, e1, fmaf(w.wk00, e0, kv.x)));
    float m1 = elu_f(fmaf(w.wk11, e1, fmaf(w.wk10, e0, kv.y)));
    // ---- LSTM2 ----
    float g2[8];
    #pragma unroll
    for (int j = 0; j < 8; ++j)
        g2[j] = fmaf(w.wh2[j][1], s.h2y, fmaf(w.wh2[j][0], s.h2x,
                fmaf(w.wi2[j][1], m1, fmaf(w.wi2[j][0], m0, w.bb2[j]))));
    s.c2x = fmaf(sig_f(g2[2]), s.c2x, sig_f(g2[0]) * tanh_f(g2[4]));
    s.c2y = fmaf(sig_f(g2[3]), s.c2y, sig_f(g2[1]) * tanh_f(g2[5]));
    s.h2x = sig_f(g2[6]) * tanh_f(s.c2x);
    s.h2y = sig_f(g2[7]) * tanh_f(s.c2y);
}

// One body step: LSTM step -> d3/d2 -> 25 outputs using prefetched x row XR.
#define BODY_STEP(I, XR)                                                        \
    do {                                                                        \
        lstm_step(s, __half22float2(zs[W_WARM + (I)][tid]), knv[l0 + (I)], w);  \
        float e0 = elu_f(s.h2x), e1 = elu_f(s.h2y);                             \
        float d3[4];                                                            \
        _Pragma("unroll")                                                       \
        for (int r = 0; r < 4; ++r)                                             \
            d3[r] = elu_f(fmaf(W_dec3[r * 2 + 1], e1,                           \
                          fmaf(W_dec3[r * 2], e0, b_dec3[r])));                 \
        float d2[8];                                                            \
        _Pragma("unroll")                                                       \
        for (int r = 0; r < 8; ++r) {                                           \
            float a = b_dec2[r];                                                \
            _Pragma("unroll")                                                   \
            for (int j = 0; j < 4; ++j) a = fmaf(W_dec2[r * 4 + j], d3[j], a);  \
            d2[r] = elu_f(a);                                                   \
        }                                                                       \
        _Pragma("unroll")                                                       \
        for (int t = 0; t < TDIM; ++t) {                                        \
            float a = b_dec[t] + XR[t];                                         \
            _Pragma("unroll")                                                   \
            for (int r = 0; r < 8; ++r) a = fmaf(W_dec[t * 8 + r], d2[r], a);   \
            if (active)                                                         \
                ob[((size_t)(l0 + (I)) * TDIM + t) * BDIM] = elu_f(a);          \
        }                                                                       \
    } while (0)

#define PREFETCH_ROW(I, XR)                                                     \
    do {                                                                        \
        _Pragma("unroll")                                                       \
        for (int t = 0; t < TDIM; ++t)                                          \
            XR[t] = xb[((size_t)(l0 + (I)) * TDIM + t) * BDIM];                 \
    } while (0)

__global__ __launch_bounds__(64) void k_fused(
    const __half2* __restrict__ z_enc, const float* __restrict__ kn,
    const float* __restrict__ Wih1, const float* __restrict__ Whh1,
    const float* __restrict__ bih1, const float* __restrict__ bhh1,
    const float* __restrict__ Wk,
    const float* __restrict__ Wih2, const float* __restrict__ Whh2,
    const float* __restrict__ bih2, const float* __restrict__ bhh2,
    const float* __restrict__ W_dec3, const float* __restrict__ b_dec3,
    const float* __restrict__ W_dec2, const float* __restrict__ b_dec2,
    const float* __restrict__ W_dec, const float* __restrict__ b_dec,
    const float* __restrict__ x, float* __restrict__ out)
{
    __shared__ __half2 zs[TOT][64];

    const int tid = threadIdx.x;
    const int b = blockIdx.x * 64 + tid;
    const int bb = b < BDIM ? b : BDIM - 1;     // clamp for safe reads
    const bool active = b < BDIM;
    const int chunk = blockIdx.y;
    const int l0 = chunk * S_CHUNK;
    const int ls = l0 - W_WARM;                 // may be negative (chunks 0..1)

    const float2* knv = reinterpret_cast<const float2*>(kn);

    // ---- stage z window into LDS (24 independent coalesced loads) ----
    #pragma unroll
    for (int i = 0; i < TOT; ++i) {
        int l = ls + i; int lc = l < 0 ? 0 : l;
        zs[i][tid] = z_enc[(size_t)lc * BDIM + bb];
    }

    // ---- prefetch x rows for body steps 0,1 (latency hidden under warmup) ----
    const float* xb = x + bb;
    float xr0[TDIM], xr1[TDIM];
    PREFETCH_ROW(0, xr0);
    PREFETCH_ROW(1, xr1);

    __syncthreads();

    // ---- weights (lane-invariant -> scalar regs) ----
    LWeights w;
    #pragma unroll
    for (int j = 0; j < 8; ++j) {
        w.wi1[j][0] = Wih1[j * 2]; w.wi1[j][1] = Wih1[j * 2 + 1];
        w.wh1[j][0] = Whh1[j * 2]; w.wh1[j][1] = Whh1[j * 2 + 1];
        w.bb1[j] = bih1[j] + bhh1[j];
        w.wi2[j][0] = Wih2[j * 2]; w.wi2[j][1] = Wih2[j * 2 + 1];
        w.wh2[j][0] = Whh2[j * 2]; w.wh2[j][1] = Whh2[j * 2 + 1];
        w.bb2[j] = bih2[j] + bhh2[j];
    }
    w.wk00 = Wk[0]; w.wk01 = Wk[1]; w.wk10 = Wk[5]; w.wk11 = Wk[6];

    LState s = {0.f, 0.f, 0.f, 0.f, 0.f, 0.f, 0.f, 0.f};

    // ---- warmup (no output) ----
    #pragma unroll 4
    for (int i = 0; i < W_WARM; ++i) {
        const int l = ls + i;
        if (l < 0) continue;                    // wave-uniform: state stays zero
        lstm_step(s, __half22float2(zs[i][tid]), knv[l], w);
    }

    float* ob = out + b;

    // ---- body: compute + interleaved IO, x prefetched 2 steps ahead ----
    BODY_STEP(0, xr0); PREFETCH_ROW(2, xr0);
    BODY_STEP(1, xr1); PREFETCH_ROW(3, xr1);
    BODY_STEP(2, xr0); PREFETCH_ROW(4, xr0);
    BODY_STEP(3, xr1); PREFETCH_ROW(5, xr1);
    BODY_STEP(4, xr0); PREFETCH_ROW(6, xr0);
    BODY_STEP(5, xr1); PREFETCH_ROW(7, xr1);
    BODY_STEP(6, xr0);
    BODY_STEP(7, xr1);
}

extern "C" void kernel_launch(void* const* d_in, const int* in_sizes, int n_in,
                              void* d_out, int out_size, void* d_ws, size_t ws_size,
                              hipStream_t stream) {
    (void)in_sizes; (void)n_in; (void)out_size; (void)ws_size;
    const float* x_input = (const float*)d_in[0];
    const float* knobs   = (const float*)d_in[1];
    const float* W_enc   = (const float*)d_in[2];
    const float* b_enc   = (const float*)d_in[3];
    const float* W_enc2  = (const float*)d_in[4];
    const float* b_enc2  = (const float*)d_in[5];
    const float* W_enc3  = (const float*)d_in[6];
    const float* b_enc3  = (const float*)d_in[7];
    const float* Wih1    = (const float*)d_in[8];
    const float* Whh1    = (const float*)d_in[9];
    const float* bih1    = (const float*)d_in[10];
    const float* bhh1    = (const float*)d_in[11];
    const float* W_knobs = (const float*)d_in[12];
    const float* b_knobs = (const float*)d_in[13];
    const float* Wih2    = (const float*)d_in[14];
    const float* Whh2    = (const float*)d_in[15];
    const float* bih2    = (const float*)d_in[16];
    const float* bhh2    = (const float*)d_in[17];
    const float* W_dec3  = (const float*)d_in[18];
    const float* b_dec3  = (const float*)d_in[19];
    const float* W_dec2  = (const float*)d_in[20];
    const float* b_dec2  = (const float*)d_in[21];
    const float* W_dec   = (const float*)d_in[22];
    const float* b_dec   = (const float*)d_in[23];

    __half2* z_enc = (__half2*)d_ws;                       // L*B half2 (4.2 MB)
    float* kn = (float*)((char*)d_ws + (size_t)LSEQ * BDIM * sizeof(__half2));

    k_enc<<<dim3(LSEQ), dim3(320), 0, stream>>>(
        x_input, knobs, W_enc, b_enc, W_enc2, b_enc2, W_enc3, b_enc3,
        W_knobs, b_knobs, z_enc, kn);
    k_fused<<<dim3((BDIM + 63) / 64, NCHUNK), dim3(64), 0, stream>>>(
        z_enc, kn, Wih1, Whh1, bih1, bhh1, W_knobs,
        Wih2, Whh2, bih2, bhh2,
        W_dec3, b_dec3, W_dec2, b_dec2, W_dec, b_dec,
        x_input, (float*)d_out);
}

// Round 8
// 88.932 us; speedup vs baseline: 1.1727x; 1.0583x over previous
//
#include <hip/hip_runtime.h>
#include <hip/hip_fp16.h>
#include <math.h>

#define LSEQ 4096
#define TDIM 25
#define BDIM 257
#define RDIM 8
#define KDIM 3

#define S_CHUNK 8
#define W_WARM 12
#define TOT (S_CHUNK + W_WARM)     // 20 steps per thread
#define NCHUNK (LSEQ / S_CHUNK)    // 512

typedef float f2 __attribute__((ext_vector_type(2)));
#define LOG2E 1.44269504f

__device__ __forceinline__ float rcp_f(float x) {
    return __builtin_amdgcn_rcpf(x);    // v_rcp_f32, ~1 ULP
}
__device__ __forceinline__ float ex2(float x) {
#if defined(__has_builtin)
#if __has_builtin(__builtin_amdgcn_exp2f)
    return __builtin_amdgcn_exp2f(x);   // v_exp_f32 (2^x)
#else
    return __expf(x * 0.69314718f);
#endif
#else
    return __expf(x * 0.69314718f);
#endif
}
__device__ __forceinline__ float elu_f(float x) {
    return x > 0.f ? x : (ex2(x * LOG2E) - 1.f);
}
// component-wise over f2; adds/muls/fma packed (v_pk_*), exp/rcp scalar
__device__ __forceinline__ f2 sig2(f2 v) {
    f2 t = v * (-LOG2E);
    f2 e; e.x = ex2(t.x); e.y = ex2(t.y);
    f2 d = e + 1.f;
    f2 r; r.x = rcp_f(d.x); r.y = rcp_f(d.y);
    return r;
}
__device__ __forceinline__ f2 tanh2(f2 v) {
    f2 t = v * (2.f * LOG2E);
    f2 e; e.x = ex2(t.x); e.y = ex2(t.y);
    f2 d = e + 1.f;
    f2 r; r.x = rcp_f(d.x); r.y = rcp_f(d.y);
    return 1.f - 2.f * r;
}
__device__ __forceinline__ f2 elu2(f2 v) {
    f2 t = v * LOG2E;
    f2 e; e.x = ex2(t.x); e.y = ex2(t.y);
    f2 em = e - 1.f;
    f2 r; r.x = v.x > 0.f ? v.x : em.x;
    r.y = v.y > 0.f ? v.y : em.y;
    return r;
}
__device__ __forceinline__ f2 ld2(const float* p, int i0, int i1) {
    f2 r; r.x = p[i0]; r.y = p[i1]; return r;
}

// ---------------- Kernel 1: encoder (parallel over L x B) ----------------
__global__ __launch_bounds__(320) void k_enc(
    const float* __restrict__ x, const float* __restrict__ knobs,
    const float* __restrict__ W_enc, const float* __restrict__ b_enc,
    const float* __restrict__ W_enc2, const float* __restrict__ b_enc2,
    const float* __restrict__ W_enc3, const float* __restrict__ b_enc3,
    const float* __restrict__ Wk, const float* __restrict__ bk,
    __half2* __restrict__ z_enc, float* __restrict__ kn)
{
    const int l = blockIdx.x;
    const int b = threadIdx.x;
    if (b < BDIM) {
        const float* xl = x + (size_t)l * TDIM * BDIM + b;
        float xr[TDIM];
        #pragma unroll
        for (int t = 0; t < TDIM; ++t) xr[t] = xl[(size_t)t * BDIM];
        float z1[RDIM];
        #pragma unroll
        for (int r = 0; r < RDIM; ++r) {
            float a = b_enc[r];
            #pragma unroll
            for (int t = 0; t < TDIM; ++t) a = fmaf(W_enc[r * TDIM + t], xr[t], a);
            z1[r] = elu_f(a);
        }
        float z2[RDIM / 2];
        #pragma unroll
        for (int r = 0; r < RDIM / 2; ++r) {
            float a = b_enc2[r];
            #pragma unroll
            for (int j = 0; j < RDIM; ++j) a = fmaf(W_enc2[r * RDIM + j], z1[j], a);
            z2[r] = elu_f(a);
        }
        float z30 = b_enc3[0], z31 = b_enc3[1];
        #pragma unroll
        for (int j = 0; j < RDIM / 2; ++j) {
            z30 = fmaf(W_enc3[j], z2[j], z30);
            z31 = fmaf(W_enc3[RDIM / 2 + j], z2[j], z31);
        }
        z_enc[(size_t)l * BDIM + b] = __floats2half2_rn(elu_f(z30), elu_f(z31));
    } else if (b == BDIM) {
        float k0 = knobs[l * KDIM + 0], k1 = knobs[l * KDIM + 1], k2 = knobs[l * KDIM + 2];
        float2 kv;
        kv.x = bk[0] + Wk[0 * 5 + 2] * k0 + Wk[0 * 5 + 3] * k1 + Wk[0 * 5 + 4] * k2;
        kv.y = bk[1] + Wk[1 * 5 + 2] * k0 + Wk[1 * 5 + 3] * k1 + Wk[1 * 5 + 4] * k2;
        reinterpret_cast<float2*>(kn)[l] = kv;
    }
}

// ---------------- Kernel 2: fused LSTM1 -> mid -> LSTM2 -> decoder (packed f32) ----------------
// Gate rows (PyTorch order): 0,1=i  2,3=f  4,5=g  6,7=o ; pairs k: {2k,2k+1}
struct PW {
    f2 xa1[4], xb1[4], ha1[4], hb1[4], b1[4];   // LSTM1
    f2 xa2[4], xb2[4], ha2[4], hb2[4], b2g[4];  // LSTM2
    f2 k0, k1;                                   // mid (h-columns of W_knobs)
};
struct LS { f2 h1, c1, h2, c2; };

__device__ __forceinline__ void lstm_step(LS& s, f2 xe, f2 kv, const PW& w)
{
    // ---- LSTM1 ----
    f2 G0 = w.xa1[0] * xe.x + w.xb1[0] * xe.y + w.ha1[0] * s.h1.x + w.hb1[0] * s.h1.y + w.b1[0];
    f2 G1 = w.xa1[1] * xe.x + w.xb1[1] * xe.y + w.ha1[1] * s.h1.x + w.hb1[1] * s.h1.y + w.b1[1];
    f2 G2 = w.xa1[2] * xe.x + w.xb1[2] * xe.y + w.ha1[2] * s.h1.x + w.hb1[2] * s.h1.y + w.b1[2];
    f2 G3 = w.xa1[3] * xe.x + w.xb1[3] * xe.y + w.ha1[3] * s.h1.x + w.hb1[3] * s.h1.y + w.b1[3];
    s.c1 = sig2(G1) * s.c1 + sig2(G0) * tanh2(G2);
    s.h1 = sig2(G3) * tanh2(s.c1);
    // ---- mid (knobs) layer ----
    f2 e = elu2(s.h1);
    f2 m = elu2(w.k0 * e.x + w.k1 * e.y + kv);
    // ---- LSTM2 ----
    f2 H0 = w.xa2[0] * m.x + w.xb2[0] * m.y + w.ha2[0] * s.h2.x + w.hb2[0] * s.h2.y + w.b2g[0];
    f2 H1 = w.xa2[1] * m.x + w.xb2[1] * m.y + w.ha2[1] * s.h2.x + w.hb2[1] * s.h2.y + w.b2g[1];
    f2 H2 = w.xa2[2] * m.x + w.xb2[2] * m.y + w.ha2[2] * s.h2.x + w.hb2[2] * s.h2.y + w.b2g[2];
    f2 H3 = w.xa2[3] * m.x + w.xb2[3] * m.y + w.ha2[3] * s.h2.x + w.hb2[3] * s.h2.y + w.b2g[3];
    s.c2 = sig2(H1) * s.c2 + sig2(H0) * tanh2(H2);
    s.h2 = sig2(H3) * tanh2(s.c2);
}

__global__ __launch_bounds__(64) void k_fused(
    const __half2* __restrict__ z_enc, const float* __restrict__ kn,
    const float* __restrict__ Wih1, const float* __restrict__ Whh1,
    const float* __restrict__ bih1, const float* __restrict__ bhh1,
    const float* __restrict__ Wk,
    const float* __restrict__ Wih2, const float* __restrict__ Whh2,
    const float* __restrict__ bih2, const float* __restrict__ bhh2,
    const float* __restrict__ W_dec3, const float* __restrict__ b_dec3,
    const float* __restrict__ W_dec2, const float* __restrict__ b_dec2,
    const float* __restrict__ W_dec, const float* __restrict__ b_dec,
    const float* __restrict__ x, float* __restrict__ out)
{
    __shared__ __half2 zs[TOT][64];

    const int tid = threadIdx.x;
    const int b = blockIdx.x * 64 + tid;
    const int bb = b < BDIM ? b : BDIM - 1;     // clamp for safe reads
    const bool active = b < BDIM;
    const int chunk = blockIdx.y;
    const int l0 = chunk * S_CHUNK;
    const int ls = l0 - W_WARM;                 // negative for chunks 0..1

    const f2* knv = reinterpret_cast<const f2*>(kn);

    // ---- stage z window into LDS (20 independent coalesced loads) ----
    #pragma unroll
    for (int i = 0; i < TOT; ++i) {
        int l = ls + i; int lc = l < 0 ? 0 : l;
        zs[i][tid] = z_enc[(size_t)lc * BDIM + bb];
    }
    __syncthreads();

    // ---- packed weights (lane-invariant) ----
    PW w;
    #pragma unroll
    for (int k = 0; k < 4; ++k) {
        w.xa1[k] = ld2(Wih1, 4 * k, 4 * k + 2);
        w.xb1[k] = ld2(Wih1, 4 * k + 1, 4 * k + 3);
        w.ha1[k] = ld2(Whh1, 4 * k, 4 * k + 2);
        w.hb1[k] = ld2(Whh1, 4 * k + 1, 4 * k + 3);
        w.b1[k]  = ld2(bih1, 2 * k, 2 * k + 1) + ld2(bhh1, 2 * k, 2 * k + 1);
        w.xa2[k] = ld2(Wih2, 4 * k, 4 * k + 2);
        w.xb2[k] = ld2(Wih2, 4 * k + 1, 4 * k + 3);
        w.ha2[k] = ld2(Whh2, 4 * k, 4 * k + 2);
        w.hb2[k] = ld2(Whh2, 4 * k + 1, 4 * k + 3);
        w.b2g[k] = ld2(bih2, 2 * k, 2 * k + 1) + ld2(bhh2, 2 * k, 2 * k + 1);
    }
    w.k0 = ld2(Wk, 0, 5);
    w.k1 = ld2(Wk, 1, 6);

    LS s; s.h1 = 0.f; s.c1 = 0.f; s.h2 = 0.f; s.c2 = 0.f;

    // ---- warmup (no output) ----
    #pragma unroll 4
    for (int i = 0; i < W_WARM; ++i) {
        const int l = ls + i;
        if (l < 0) continue;                    // wave-uniform: state stays zero
        float2 xf = __half22float2(zs[i][tid]);
        f2 xe; xe.x = xf.x; xe.y = xf.y;
        lstm_step(s, xe, knv[l], w);
    }

    // ---- body: LSTM + dec3/dec2, keep d2 pairs in registers ----
    f2 d3a0 = ld2(W_dec3, 0, 2), d3b0 = ld2(W_dec3, 1, 3), bb30 = ld2(b_dec3, 0, 1);
    f2 d3a1 = ld2(W_dec3, 4, 6), d3b1 = ld2(W_dec3, 5, 7), bb31 = ld2(b_dec3, 2, 3);

    f2 d2a[S_CHUNK][4];
    #pragma unroll
    for (int i = 0; i < S_CHUNK; ++i) {
        float2 xf = __half22float2(zs[W_WARM + i][tid]);
        f2 xe; xe.x = xf.x; xe.y = xf.y;
        lstm_step(s, xe, knv[l0 + i], w);
        f2 e = elu2(s.h2);
        f2 d3p0 = elu2(d3a0 * e.x + d3b0 * e.y + bb30);   // dec3 rows 0,1
        f2 d3p1 = elu2(d3a1 * e.x + d3b1 * e.y + bb31);   // dec3 rows 2,3
        #pragma unroll
        for (int k = 0; k < 4; ++k) {
            f2 a = ld2(W_dec2, 8 * k, 8 * k + 4) * d3p0.x
                 + ld2(W_dec2, 8 * k + 1, 8 * k + 5) * d3p0.y
                 + ld2(W_dec2, 8 * k + 2, 8 * k + 6) * d3p1.x
                 + ld2(W_dec2, 8 * k + 3, 8 * k + 7) * d3p1.y
                 + ld2(b_dec2, 2 * k, 2 * k + 1);
            d2a[i][k] = elu2(a);
        }
    }

    // ---- output: t outer so W_dec row (scalar loads) amortizes over 8 l's ----
    const float* xb = x + bb;
    float* ob = out + b;
    #pragma unroll 5
    for (int t = 0; t < TDIM; ++t) {
        f2 wt0 = ld2(W_dec, t * 8 + 0, t * 8 + 1);
        f2 wt1 = ld2(W_dec, t * 8 + 2, t * 8 + 3);
        f2 wt2 = ld2(W_dec, t * 8 + 4, t * 8 + 5);
        f2 wt3 = ld2(W_dec, t * 8 + 6, t * 8 + 7);
        const float bt = b_dec[t];
        float res[S_CHUNK];
        #pragma unroll
        for (int i = 0; i < S_CHUNK; ++i) {
            const int idx = ((l0 + i) * TDIM + t) * BDIM;
            f2 ap = wt0 * d2a[i][0] + wt1 * d2a[i][1] + wt2 * d2a[i][2] + wt3 * d2a[i][3];
            float a = ap.x + ap.y + bt + xb[idx];
            res[i] = elu_f(a);
        }
        if (active) {
            #pragma unroll
            for (int i = 0; i < S_CHUNK; ++i)
                ob[((l0 + i) * TDIM + t) * BDIM] = res[i];
        }
    }
}

extern "C" void kernel_launch(void* const* d_in, const int* in_sizes, int n_in,
                              void* d_out, int out_size, void* d_ws, size_t ws_size,
                              hipStream_t stream) {
    (void)in_sizes; (void)n_in; (void)out_size; (void)ws_size;
    const float* x_input = (const float*)d_in[0];
    const float* knobs   = (const float*)d_in[1];
    const float* W_enc   = (const float*)d_in[2];
    const float* b_enc   = (const float*)d_in[3];
    const float* W_enc2  = (const float*)d_in[4];
    const float* b_enc2  = (const float*)d_in[5];
    const float* W_enc3  = (const float*)d_in[6];
    const float* b_enc3  = (const float*)d_in[7];
    const float* Wih1    = (const float*)d_in[8];
    const float* Whh1    = (const float*)d_in[9];
    const float* bih1    = (const float*)d_in[10];
    const float* bhh1    = (const float*)d_in[11];
    const float* W_knobs = (const float*)d_in[12];
    const float* b_knobs = (const float*)d_in[13];
    const float* Wih2    = (const float*)d_in[14];
    const float* Whh2    = (const float*)d_in[15];
    const float* bih2    = (const float*)d_in[16];
    const float* bhh2    = (const float*)d_in[17];
    const float* W_dec3  = (const float*)d_in[18];
    const float* b_dec3  = (const float*)d_in[19];
    const float* W_dec2  = (const float*)d_in[20];
    const float* b_dec2  = (const float*)d_in[21];
    const float* W_dec   = (const float*)d_in[22];
    const float* b_dec   = (const float*)d_in[23];

    __half2* z_enc = (__half2*)d_ws;                       // L*B half2 (4.2 MB)
    float* kn = (float*)((char*)d_ws + (size_t)LSEQ * BDIM * sizeof(__half2));

    k_enc<<<dim3(LSEQ), dim3(320), 0, stream>>>(
        x_input, knobs, W_enc, b_enc, W_enc2, b_enc2, W_enc3, b_enc3,
        W_knobs, b_knobs, z_enc, kn);
    k_fused<<<dim3((BDIM + 63) / 64, NCHUNK), dim3(64), 0, stream>>>(
        z_enc, kn, Wih1, Whh1, bih1, bhh1, W_knobs,
        Wih2, Whh2, bih2, bhh2,
        W_dec3, b_dec3, W_dec2, b_dec2, W_dec, b_dec,
        x_input, (float*)d_out);
}